// Round 3
// baseline (176.713 us; speedup 1.0000x reference)
//
#include <hip/hip_runtime.h>
#include <stdint.h>

#define N_DIM 4096
#define B_DIM 64

typedef __bf16 bf16x8 __attribute__((ext_vector_type(8)));
typedef float floatx4 __attribute__((ext_vector_type(4)));

union FragU { uint4 u; bf16x8 h; };

__device__ __forceinline__ unsigned short f2bf_rne(float f) {
    unsigned int u = __float_as_uint(f);
    u += 0x7fffu + ((u >> 16) & 1u);
    return (unsigned short)(u >> 16);
}

// c = Vmag*cos(ang), s = Vmag*sin(ang), packed bf16 in MFMA B-fragment order:
// idx = ((j>>3)*64 + b)*8 + (j&7)   (j = bus index / K, b = batch col)
__global__ __launch_bounds__(256) void pf_prep(
        const float* __restrict__ Vmag, const float* __restrict__ Vang,
        unsigned short* __restrict__ c_pk, unsigned short* __restrict__ s_pk) {
    int idx = blockIdx.x * 256 + threadIdx.x;   // = b*4096 + j
    int b = idx >> 12;
    int j = idx & 4095;
    float sv, cv;
    sincosf(Vang[idx], &sv, &cv);
    float v = Vmag[idx];
    int p = (((j >> 3) << 6) + b) * 8 + (j & 7);
    c_pk[p] = f2bf_rne(v * cv);
    s_pk[p] = f2bf_rne(v * sv);
}

// Inline-asm loads: volatile pins program order (the compiler sank/serialized
// every source-level prefetch in rounds 1-2: VGPR_Count 44/32 proved it);
// asm-defined result registers cannot be rematerialized or sunk, so the
// software pipeline is structural. Waits are hand-counted vmcnt(N) + rule-18
// sched_barrier(0) fences (compiler doesn't know asm outputs are loads, so
// nothing else orders the consumers).
__device__ __forceinline__ float4 aload_f4(const float* base, uint32_t boff) {
    float4 d;
    asm volatile("global_load_dwordx4 %0, %1, %2"
                 : "=v"(d) : "v"(boff), "s"(base));
    return d;
}
__device__ __forceinline__ uint4 aload_u4(const unsigned short* base, uint32_t boff) {
    uint4 d;
    asm volatile("global_load_dwordx4 %0, %1, %2"
                 : "=v"(d) : "v"(boff), "s"(base));
    return d;
}

// Block = 16 rows, 16 waves = (colhalf ch, K-eighth w8); wave: 16 rows x
// 32 cols x 512 K in 16 steps of K=32. Pipeline: A (HBM) issued 2 steps
// ahead, c/s (L2-resident, 1MB shared) 1 step ahead. Per-iter queue after
// issues: [A(t+1) A(t+2) cs(t) cs(t+1)] minus drained -> s_waitcnt vmcnt(8)
// leaves exactly [A(t+2), cs(t+1)] in flight during compute(t). ~8KB in
// flight per wave sustained = ~128KB/CU >> Little's-law need (~9KB).
// X = G*c + B*s ; Y = G*s - B*c (-c via sign-bit XOR).
__global__ __launch_bounds__(1024) void pf_gemm(
        const float* __restrict__ G, const float* __restrict__ Bm,
        const unsigned short* __restrict__ c_pk, const unsigned short* __restrict__ s_pk,
        const float* __restrict__ Vmag, const float* __restrict__ Vang,
        const float* __restrict__ P_in, const float* __restrict__ Q_in,
        float* __restrict__ out) {
    __shared__ __align__(16) float red[2 * 4 * 16 * 66];   // 33792 B
    const int tid = threadIdx.x;
    const int wave = tid >> 6;        // 0..15
    const int lane = tid & 63;
    const int n = lane & 15;          // A: row ; B/CD: col (batch)
    const int quad = lane >> 4;       // k-subgroup of 8
    const int ch = wave & 1;          // column half (0: b 0..31, 1: b 32..63)
    const int w8 = wave >> 1;         // K-eighth (512 K each)
    const int i0 = blockIdx.x << 4;   // 16 rows per block

    // byte offsets (fit in u32: G/B are 64 MB, cs 512 KB)
    const uint32_t goff  = ((uint32_t)(i0 + n) * N_DIM + w8 * 512 + quad * 8) * 4u;
    const uint32_t csoff = ((uint32_t)((w8 * 64 + quad) * 64) + ch * 32 + n) * 16u;

    floatx4 accX[2], accY[2];
    #pragma unroll
    for (int t16 = 0; t16 < 2; ++t16) {
        accX[t16] = (floatx4){0.f, 0.f, 0.f, 0.f};
        accY[t16] = (floatx4){0.f, 0.f, 0.f, 0.f};
    }

    float4 gA[3][2], hA[3][2];   // A fp32 staging, 3 generations (t, t+1, t+2)
    uint4  cu[2][2], su[2][2];   // c/s staging, 2 generations (t, t+1)

    // prologue, queue order matters: A(0)[4], A(1)[4], cs(0)[4]
    gA[0][0] = aload_f4(G,  goff);
    gA[0][1] = aload_f4(G,  goff + 16);
    hA[0][0] = aload_f4(Bm, goff);
    hA[0][1] = aload_f4(Bm, goff + 16);
    gA[1][0] = aload_f4(G,  goff + 128);
    gA[1][1] = aload_f4(G,  goff + 144);
    hA[1][0] = aload_f4(Bm, goff + 128);
    hA[1][1] = aload_f4(Bm, goff + 144);
    cu[0][0] = aload_u4(c_pk, csoff);
    cu[0][1] = aload_u4(c_pk, csoff + 256);
    su[0][0] = aload_u4(s_pk, csoff);
    su[0][1] = aload_u4(s_pk, csoff + 256);

    #pragma unroll
    for (int t = 0; t < 16; ++t) {
        // issue A(t+2): 4 loads
        if (t + 2 < 16) {
            const uint32_t og = goff + (uint32_t)(t + 2) * 128u;
            gA[(t + 2) % 3][0] = aload_f4(G,  og);
            gA[(t + 2) % 3][1] = aload_f4(G,  og + 16);
            hA[(t + 2) % 3][0] = aload_f4(Bm, og);
            hA[(t + 2) % 3][1] = aload_f4(Bm, og + 16);
        }
        // issue cs(t+1): 4 loads
        if (t + 1 < 16) {
            const uint32_t oc = csoff + (uint32_t)(t + 1) * 4096u;
            cu[(t + 1) & 1][0] = aload_u4(c_pk, oc);
            cu[(t + 1) & 1][1] = aload_u4(c_pk, oc + 256);
            su[(t + 1) & 1][0] = aload_u4(s_pk, oc);
            su[(t + 1) & 1][1] = aload_u4(s_pk, oc + 256);
        }
        __builtin_amdgcn_sched_barrier(0);
        // counted wait: A(t) and cs(t) complete; [A(t+2), cs(t+1)] stay in
        // flight. Tail: t=14 leaves cs(15) only; t=15 drains all.
        if (t < 14)       asm volatile("s_waitcnt vmcnt(8)");
        else if (t == 14) asm volatile("s_waitcnt vmcnt(4)");
        else              asm volatile("s_waitcnt vmcnt(0)");
        __builtin_amdgcn_sched_barrier(0);

        // convert A(t) fp32 -> bf16
        const float4 g0 = gA[t % 3][0], g1 = gA[t % 3][1];
        const float4 h0 = hA[t % 3][0], h1 = hA[t % 3][1];
        bf16x8 ag, ah;
        ag[0] = (__bf16)g0.x; ag[1] = (__bf16)g0.y; ag[2] = (__bf16)g0.z; ag[3] = (__bf16)g0.w;
        ag[4] = (__bf16)g1.x; ag[5] = (__bf16)g1.y; ag[6] = (__bf16)g1.z; ag[7] = (__bf16)g1.w;
        ah[0] = (__bf16)h0.x; ah[1] = (__bf16)h0.y; ah[2] = (__bf16)h0.z; ah[3] = (__bf16)h0.w;
        ah[4] = (__bf16)h1.x; ah[5] = (__bf16)h1.y; ah[6] = (__bf16)h1.z; ah[7] = (__bf16)h1.w;

        // c-phase: X += G*c ; Y += B*(-c)
        #pragma unroll
        for (int t16 = 0; t16 < 2; ++t16) {
            FragU cf, nf;
            cf.u = cu[t & 1][t16];
            nf.u.x = cf.u.x ^ 0x80008000u;
            nf.u.y = cf.u.y ^ 0x80008000u;
            nf.u.z = cf.u.z ^ 0x80008000u;
            nf.u.w = cf.u.w ^ 0x80008000u;
            accX[t16] = __builtin_amdgcn_mfma_f32_16x16x32_bf16(ag, cf.h, accX[t16], 0, 0, 0);
            accY[t16] = __builtin_amdgcn_mfma_f32_16x16x32_bf16(ah, nf.h, accY[t16], 0, 0, 0);
        }
        // s-phase: X += B*s ; Y += G*s
        #pragma unroll
        for (int t16 = 0; t16 < 2; ++t16) {
            FragU sf;
            sf.u = su[t & 1][t16];
            accX[t16] = __builtin_amdgcn_mfma_f32_16x16x32_bf16(ah, sf.h, accX[t16], 0, 0, 0);
            accY[t16] = __builtin_amdgcn_mfma_f32_16x16x32_bf16(ag, sf.h, accY[t16], 0, 0, 0);
        }
    }

    // cross-wave reduction over the 8 K-eighth waves per column half.
    // C/D layout: col(b)=lane&15, row(m)=quad*4+reg
    #define RED(x, wp, m, b) red[(((x) * 4 + (wp)) * 16 + (m)) * 66 + (b)]
    if (w8 >= 4) {
        #pragma unroll
        for (int t16 = 0; t16 < 2; ++t16)
            #pragma unroll
            for (int r = 0; r < 4; ++r) {
                RED(0, w8 - 4, (quad << 2) + r, ch * 32 + (t16 << 4) + n) = accX[t16][r];
                RED(1, w8 - 4, (quad << 2) + r, ch * 32 + (t16 << 4) + n) = accY[t16][r];
            }
    }
    __syncthreads();
    if (w8 < 4) {
        #pragma unroll
        for (int t16 = 0; t16 < 2; ++t16)
            #pragma unroll
            for (int r = 0; r < 4; ++r) {
                RED(0, w8, (quad << 2) + r, ch * 32 + (t16 << 4) + n) += accX[t16][r];
                RED(1, w8, (quad << 2) + r, ch * 32 + (t16 << 4) + n) += accY[t16][r];
            }
    }
    __syncthreads();

    // 1024 outputs (m,b); 1024 threads -> 1 each; fused epilogue.
    // c,s recomputed from Vmag/Vang (bitwise-identical to prep's fp32 math).
    {
        int bb = tid >> 4;
        int m = tid & 15;
        float X = 0.f, Y = 0.f;
        #pragma unroll
        for (int w = 0; w < 4; ++w) {
            X += RED(0, w, m, bb);
            Y += RED(1, w, m, bb);
        }
        size_t off = (size_t)bb * N_DIM + i0 + m;
        float sv, cv;
        sincosf(Vang[off], &sv, &cv);
        float v = Vmag[off];
        float c = v * cv;
        float s = v * sv;
        out[off] = c * X + s * Y - P_in[off];                          // res_P
        out[(size_t)B_DIM * N_DIM + off] = s * X - c * Y - Q_in[off];  // res_Q
    }
}

extern "C" void kernel_launch(void* const* d_in, const int* in_sizes, int n_in,
                              void* d_out, int out_size, void* d_ws, size_t ws_size,
                              hipStream_t stream) {
    const float* Vmag = (const float*)d_in[0];
    const float* Vang = (const float*)d_in[1];
    const float* P_in = (const float*)d_in[2];
    const float* Q_in = (const float*)d_in[3];
    const float* G    = (const float*)d_in[4];
    const float* Bm   = (const float*)d_in[5];
    float* out = (float*)d_out;

    char* ws = (char*)d_ws;
    unsigned short* c_pk = (unsigned short*)(ws);                    // 512 KB
    unsigned short* s_pk = (unsigned short*)(ws + (512u << 10));     // 512 KB

    hipLaunchKernelGGL(pf_prep, dim3((B_DIM * N_DIM) / 256), dim3(256), 0, stream,
                       Vmag, Vang, c_pk, s_pk);
    hipLaunchKernelGGL(pf_gemm, dim3(N_DIM / 16), dim3(1024), 0, stream,
                       G, Bm, c_pk, s_pk, Vmag, Vang, P_in, Q_in, out);
}